// Round 1
// baseline (856.849 us; speedup 1.0000x reference)
//
#include <hip/hip_runtime.h>

#define N_NODES 100000
#define F_IN    128
#define NH      2
#define HDIM    64
#define NE      1600000
#define NG      2048
#define NEG_SLOPE 0.2f

// ws layout (float offsets)
//   xw       : 0         .. 6,400,000   [N,64]
//   a_src    : 6,400,000 .. +200,000    [N,2]
//   a_dst    : 6,600,000 .. +200,000    [N,2]
//   den      : 6,800,000 .. +200,000    [N,2]   (zeroed)
//   scoreagg : 7,000,000 .. +100,000    [N]     (zeroed)
//   gsum     : 7,100,000 .. +2,048      [G]     (zeroed)
//   p        : 7,102,048 .. +100,000    [N]
//   base     : 7,202,048 .. +100,000    [N]
//   evec     : 7,302,048 .. +100,000    [N]
// total 7,402,048 floats = 29.6 MB

__device__ __forceinline__ void atomAddF(float* a, float v) {
    unsafeAtomicAdd(a, v);   // hardware global_atomic_add_f32 on gfx950
}

// K1: xw = node @ W_gat ; a_src/a_dst per (node, head)
__global__ __launch_bounds__(256) void k_gemm(const float* __restrict__ node,
        const float* __restrict__ Wg, const float* __restrict__ att_s,
        const float* __restrict__ att_d, float* __restrict__ xw,
        float* __restrict__ a_src, float* __restrict__ a_dst) {
    __shared__ float WL[F_IN * HDIM];   // 32 KB
    int t = threadIdx.x;
    for (int i = t; i < F_IN * HDIM / 4; i += 256)
        ((float4*)WL)[i] = ((const float4*)Wg)[i];
    __syncthreads();

    int lane = t & 63;
    int wave = t >> 6;
    int r0 = blockIdx.x * 16 + wave * 4;   // 6250 blocks * 16 rows = 100000 exactly
    const float* n0 = node + (size_t)r0 * F_IN;

    float acc0 = 0.f, acc1 = 0.f, acc2 = 0.f, acc3 = 0.f;
    for (int k = 0; k < F_IN; k += 4) {
        float w0 = WL[(k + 0) * HDIM + lane];
        float w1 = WL[(k + 1) * HDIM + lane];
        float w2 = WL[(k + 2) * HDIM + lane];
        float w3 = WL[(k + 3) * HDIM + lane];
        float4 v;
        v = *(const float4*)(n0 + 0 * F_IN + k);
        acc0 += v.x * w0 + v.y * w1 + v.z * w2 + v.w * w3;
        v = *(const float4*)(n0 + 1 * F_IN + k);
        acc1 += v.x * w0 + v.y * w1 + v.z * w2 + v.w * w3;
        v = *(const float4*)(n0 + 2 * F_IN + k);
        acc2 += v.x * w0 + v.y * w1 + v.z * w2 + v.w * w3;
        v = *(const float4*)(n0 + 3 * F_IN + k);
        acc3 += v.x * w0 + v.y * w1 + v.z * w2 + v.w * w3;
    }

    float asv = att_s[lane];
    float adv = att_d[lane];
    float accs[4] = {acc0, acc1, acc2, acc3};
#pragma unroll
    for (int i = 0; i < 4; ++i) {
        int r = r0 + i;
        xw[(size_t)r * HDIM + lane] = accs[i];
        float sv = accs[i] * asv;
        float dv = accs[i] * adv;
#pragma unroll
        for (int m = 16; m >= 1; m >>= 1) {
            sv += __shfl_xor(sv, m, 32);
            dv += __shfl_xor(dv, m, 32);
        }
        if ((lane & 31) == 0) {
            a_src[r * 2 + (lane >> 5)] = sv;
            a_dst[r * 2 + (lane >> 5)] = dv;
        }
    }
}

// K2: per-edge message accumulation (edges + self-loops), wave per edge.
// num[dst] += e * xw[src]; den[dst,h] += e   (normalize later)
__global__ __launch_bounds__(256) void k_msg(const int* __restrict__ ei,
        const float* __restrict__ xw, const float* __restrict__ a_src,
        const float* __restrict__ a_dst, float* __restrict__ num,
        float* __restrict__ den) {
    int lane = threadIdx.x & 63;
    int eid = blockIdx.x * 4 + (threadIdx.x >> 6);
    if (eid >= NE + N_NODES) return;
    int s, d;
    if (eid < NE) { s = ei[eid]; d = ei[NE + eid]; }
    else          { s = d = eid - NE; }
    int h = lane >> 5;
    float lg = a_src[s * 2 + h] + a_dst[d * 2 + h];
    lg = lg > 0.f ? lg : NEG_SLOPE * lg;
    float e = __expf(lg);
    float xv = xw[(size_t)s * HDIM + lane];
    atomAddF(&num[(size_t)d * HDIM + lane], xv * e);
    if ((lane & 31) == 0) atomAddF(&den[d * 2 + h], e);
}

// K3: x = num/den + bias (in place in d_out); p = x.w_rel ; base = x.w_root + b_rel
__global__ __launch_bounds__(256) void k_norm(float* __restrict__ x,
        const float* __restrict__ den, const float* __restrict__ bias,
        const float* __restrict__ wrel, const float* __restrict__ wroot,
        const float* __restrict__ brel, float* __restrict__ p,
        float* __restrict__ base) {
    int lane = threadIdx.x & 63;
    int n = blockIdx.x * 4 + (threadIdx.x >> 6);
    if (n >= N_NODES) return;
    float v = x[(size_t)n * HDIM + lane] / den[n * 2 + (lane >> 5)] + bias[lane];
    x[(size_t)n * HDIM + lane] = v;
    float pv = v * wrel[lane];
    float rv = v * wroot[lane];
#pragma unroll
    for (int m = 32; m >= 1; m >>= 1) {
        pv += __shfl_xor(pv, m, 64);
        rv += __shfl_xor(rv, m, 64);
    }
    if (lane == 0) { p[n] = pv; base[n] = rv + brel[0]; }
}

// K4: scoreagg[dst] += p[src] over original edges (dot distributed over segment_sum)
__global__ __launch_bounds__(256) void k_agg(const int* __restrict__ ei,
        const float* __restrict__ p, float* __restrict__ sa) {
    int e = blockIdx.x * 256 + threadIdx.x;
    if (e >= NE) return;
    atomAddF(&sa[ei[NE + e]], p[ei[e]]);
}

// K5: score -> exp(score), gsum[batch] += e
__global__ __launch_bounds__(256) void k_score(const float* __restrict__ sa,
        const float* __restrict__ base, const int* __restrict__ batch,
        float* __restrict__ evec, float* __restrict__ gsum) {
    int n = blockIdx.x * 256 + threadIdx.x;
    if (n >= N_NODES) return;
    float ev = __expf(sa[n] + base[n]);
    evec[n] = ev;
    atomAddF(&gsum[batch[n]], ev);
}

// K6: emb[batch[n]] += x[n] * (e[n]/gsum[batch[n]])
__global__ __launch_bounds__(256) void k_pool(const float* __restrict__ x,
        const float* __restrict__ evec, const float* __restrict__ gsum,
        const int* __restrict__ batch, float* __restrict__ emb) {
    int lane = threadIdx.x & 63;
    int n = blockIdx.x * 4 + (threadIdx.x >> 6);
    if (n >= N_NODES) return;
    int b = batch[n];
    float s = evec[n] / gsum[b];
    atomAddF(&emb[(size_t)b * HDIM + lane], x[(size_t)n * HDIM + lane] * s);
}

extern "C" void kernel_launch(void* const* d_in, const int* in_sizes, int n_in,
                              void* d_out, int out_size, void* d_ws, size_t ws_size,
                              hipStream_t stream) {
    const float* node  = (const float*)d_in[0];
    const int*   ei    = (const int*)d_in[1];
    const int*   batch = (const int*)d_in[2];
    const float* Wg    = (const float*)d_in[3];
    const float* att_s = (const float*)d_in[4];
    const float* att_d = (const float*)d_in[5];
    const float* bias  = (const float*)d_in[6];
    const float* wrel  = (const float*)d_in[7];
    const float* brel  = (const float*)d_in[8];
    const float* wroot = (const float*)d_in[9];

    float* out = (float*)d_out;
    float* emb = out + (size_t)N_NODES * HDIM;

    float* ws    = (float*)d_ws;
    float* xw    = ws;
    float* a_src = ws + 6400000;
    float* a_dst = ws + 6600000;
    float* den   = ws + 6800000;
    float* sa    = ws + 7000000;
    float* gsum  = ws + 7100000;
    float* p     = ws + 7102048;
    float* base  = ws + 7202048;
    float* evec  = ws + 7302048;

    // zero accumulators (d_out: num region + emb; ws: den..gsum block)
    hipMemsetAsync(d_out, 0, (size_t)out_size * sizeof(float), stream);
    hipMemsetAsync(den, 0, (size_t)302048 * sizeof(float), stream);

    k_gemm<<<6250, 256, 0, stream>>>(node, Wg, att_s, att_d, xw, a_src, a_dst);
    k_msg<<<(NE + N_NODES + 3) / 4, 256, 0, stream>>>(ei, xw, a_src, a_dst, out, den);
    k_norm<<<(N_NODES + 3) / 4, 256, 0, stream>>>(out, den, bias, wrel, wroot, brel, p, base);
    k_agg<<<(NE + 255) / 256, 256, 0, stream>>>(ei, p, sa);
    k_score<<<(N_NODES + 255) / 256, 256, 0, stream>>>(sa, base, batch, evec, gsum);
    k_pool<<<(N_NODES + 3) / 4, 256, 0, stream>>>(out, evec, gsum, batch, emb);
}

// Round 2
// 560.821 us; speedup vs baseline: 1.5278x; 1.5278x over previous
//
#include <hip/hip_runtime.h>

#define N_NODES 100000
#define F_IN    128
#define HDIM    64
#define NE      1600000
#define NG      2048
#define NEG_SLOPE 0.2f
#define SCAN_BLKS 392   // 392*256 >= 100000

// ws layout (element offsets, 4B each)
//   xw      : 0         [N*64]
//   a_src   : 6,400,000 [N*2]
//   a_dst   : 6,600,000 [N*2]
//   p       : 6,800,000 [N]
//   base    : 6,900,000 [N]
//   evec    : 7,000,000 [N]
//   deg     : 7,100,000 [N]      (int, zeroed)
//   cur     : 7,200,000 [N]      (int, zeroed)
//   row_ptr : 7,300,000 [N+1]    (int)
//   bsum    : 7,400,008 [392]    (int)
//   boff    : 7,400,400 [392]    (int)
//   gstart  : 7,400,792 [NG+1]   (int)
//   csr_src : 7,402,848 [NE]     (int)
// total 9,002,848 elems = 36.0 MB

// ---------- K1: xw = node @ W_gat ; a_src/a_dst per (node, head) ----------
__global__ __launch_bounds__(256) void k_gemm(const float* __restrict__ node,
        const float* __restrict__ Wg, const float* __restrict__ att_s,
        const float* __restrict__ att_d, float* __restrict__ xw,
        float* __restrict__ a_src, float* __restrict__ a_dst) {
    __shared__ float WL[F_IN * HDIM];   // 32 KB
    int t = threadIdx.x;
    for (int i = t; i < F_IN * HDIM / 4; i += 256)
        ((float4*)WL)[i] = ((const float4*)Wg)[i];
    __syncthreads();

    int lane = t & 63;
    int wave = t >> 6;
    int r0 = blockIdx.x * 16 + wave * 4;
    const float* n0 = node + (size_t)r0 * F_IN;

    float acc0 = 0.f, acc1 = 0.f, acc2 = 0.f, acc3 = 0.f;
    for (int k = 0; k < F_IN; k += 4) {
        float w0 = WL[(k + 0) * HDIM + lane];
        float w1 = WL[(k + 1) * HDIM + lane];
        float w2 = WL[(k + 2) * HDIM + lane];
        float w3 = WL[(k + 3) * HDIM + lane];
        float4 v;
        v = *(const float4*)(n0 + 0 * F_IN + k);
        acc0 += v.x * w0 + v.y * w1 + v.z * w2 + v.w * w3;
        v = *(const float4*)(n0 + 1 * F_IN + k);
        acc1 += v.x * w0 + v.y * w1 + v.z * w2 + v.w * w3;
        v = *(const float4*)(n0 + 2 * F_IN + k);
        acc2 += v.x * w0 + v.y * w1 + v.z * w2 + v.w * w3;
        v = *(const float4*)(n0 + 3 * F_IN + k);
        acc3 += v.x * w0 + v.y * w1 + v.z * w2 + v.w * w3;
    }

    float asv = att_s[lane];
    float adv = att_d[lane];
    float accs[4] = {acc0, acc1, acc2, acc3};
#pragma unroll
    for (int i = 0; i < 4; ++i) {
        int r = r0 + i;
        xw[(size_t)r * HDIM + lane] = accs[i];
        float sv = accs[i] * asv;
        float dv = accs[i] * adv;
#pragma unroll
        for (int m = 16; m >= 1; m >>= 1) {
            sv += __shfl_xor(sv, m, 32);
            dv += __shfl_xor(dv, m, 32);
        }
        if ((lane & 31) == 0) {
            a_src[r * 2 + (lane >> 5)] = sv;
            a_dst[r * 2 + (lane >> 5)] = dv;
        }
    }
}

// ---------- CSR build ----------
__global__ __launch_bounds__(256) void k_count(const int* __restrict__ ei,
        int* __restrict__ deg) {
    int e = blockIdx.x * 256 + threadIdx.x;
    if (e >= NE) return;
    atomicAdd(&deg[ei[NE + e]], 1);
}

__global__ __launch_bounds__(256) void k_blksum(const int* __restrict__ deg,
        int* __restrict__ bsum) {
    int t = threadIdx.x, b = blockIdx.x;
    int i = b * 256 + t;
    int v = (i < N_NODES) ? deg[i] : 0;
#pragma unroll
    for (int m = 32; m >= 1; m >>= 1) v += __shfl_xor(v, m, 64);
    __shared__ int ws4[4];
    if ((t & 63) == 0) ws4[t >> 6] = v;
    __syncthreads();
    if (t == 0) bsum[b] = ws4[0] + ws4[1] + ws4[2] + ws4[3];
}

__global__ __launch_bounds__(64) void k_scan_bsum(const int* __restrict__ bsum,
        int* __restrict__ boff) {
    int lane = threadIdx.x;
    int carry = 0;
    for (int c = 0; c < SCAN_BLKS; c += 64) {
        int orig = (c + lane < SCAN_BLKS) ? bsum[c + lane] : 0;
        int incl = orig;
#pragma unroll
        for (int d = 1; d < 64; d <<= 1) {
            int u = __shfl_up(incl, d, 64);
            if (lane >= d) incl += u;
        }
        if (c + lane < SCAN_BLKS) boff[c + lane] = carry + incl - orig;
        carry += __shfl(incl, 63, 64);
    }
}

__global__ __launch_bounds__(256) void k_scan_final(const int* __restrict__ deg,
        const int* __restrict__ boff, int* __restrict__ row_ptr) {
    int t = threadIdx.x, b = blockIdx.x;
    int i = b * 256 + t;
    int v = (i < N_NODES) ? deg[i] : 0;
    int lane = t & 63, w = t >> 6;
    int incl = v;
#pragma unroll
    for (int d = 1; d < 64; d <<= 1) {
        int u = __shfl_up(incl, d, 64);
        if (lane >= d) incl += u;
    }
    __shared__ int wsum[4];
    if (lane == 63) wsum[w] = incl;
    __syncthreads();
    int wb = 0;
    for (int k = 0; k < w; ++k) wb += wsum[k];
    if (i < N_NODES) row_ptr[i] = boff[b] + wb + incl - v;
    if (b == 0 && t == 0) row_ptr[N_NODES] = NE;
}

__global__ __launch_bounds__(256) void k_scatter(const int* __restrict__ ei,
        const int* __restrict__ row_ptr, int* __restrict__ cur,
        int* __restrict__ csr_src) {
    int e = blockIdx.x * 256 + threadIdx.x;
    if (e >= NE) return;
    int d = ei[NE + e];
    int pos = atomicAdd(&cur[d], 1);
    csr_src[row_ptr[d] + pos] = ei[e];
}

// ---------- K2: GAT aggregation (gather over CSR) + fused norm/dots ----------
__global__ __launch_bounds__(256) void k_gat(const int* __restrict__ row_ptr,
        const int* __restrict__ csr_src, const float* __restrict__ xw,
        const float* __restrict__ a_src, const float* __restrict__ a_dst,
        const float* __restrict__ bias, const float* __restrict__ wrel,
        const float* __restrict__ wroot, const float* __restrict__ brel,
        float* __restrict__ x_out, float* __restrict__ p,
        float* __restrict__ base) {
    int lane = threadIdx.x & 63;
    int d = blockIdx.x * 4 + (threadIdx.x >> 6);
    if (d >= N_NODES) return;
    int h = lane >> 5;

    float ad0 = a_dst[d * 2];
    float ad1 = a_dst[d * 2 + 1];
    float as0d = a_src[d * 2];
    float as1d = a_src[d * 2 + 1];

    // self loop
    float lg = (h ? (as1d + ad1) : (as0d + ad0));
    lg = lg > 0.f ? lg : NEG_SLOPE * lg;
    float e = __expf(lg);
    float acc = e * xw[(size_t)d * HDIM + lane];
    float den = e;

    int beg = row_ptr[d], end = row_ptr[d + 1];
    for (int c = beg; c < end; c += 64) {
        int nv = end - c; if (nv > 64) nv = 64;
        int s_l = 0;
        float e0 = 0.f, e1 = 0.f;
        if (c + lane < end) {
            s_l = csr_src[c + lane];
            float as0 = a_src[s_l * 2];
            float as1 = a_src[s_l * 2 + 1];
            float l0 = as0 + ad0; l0 = l0 > 0.f ? l0 : NEG_SLOPE * l0;
            float l1 = as1 + ad1; l1 = l1 > 0.f ? l1 : NEG_SLOPE * l1;
            e0 = __expf(l0);
            e1 = __expf(l1);
        }
        for (int j = 0; j < nv; ++j) {
            int s = __shfl(s_l, j, 64);
            float ee0 = __shfl(e0, j, 64);
            float ee1 = __shfl(e1, j, 64);
            float ee = h ? ee1 : ee0;
            acc += ee * xw[(size_t)s * HDIM + lane];
            den += ee;
        }
    }

    float v = acc / den + bias[lane];
    x_out[(size_t)d * HDIM + lane] = v;

    float pv = v * wrel[lane];
    float rv = v * wroot[lane];
#pragma unroll
    for (int m = 32; m >= 1; m >>= 1) {
        pv += __shfl_xor(pv, m, 64);
        rv += __shfl_xor(rv, m, 64);
    }
    if (lane == 0) { p[d] = pv; base[d] = rv + brel[0]; }
}

// ---------- K3: score aggregation over CSR -> evec ----------
__global__ __launch_bounds__(256) void k_score(const int* __restrict__ row_ptr,
        const int* __restrict__ csr_src, const float* __restrict__ p,
        const float* __restrict__ base, float* __restrict__ evec) {
    int lane = threadIdx.x & 63;
    int d = blockIdx.x * 4 + (threadIdx.x >> 6);
    if (d >= N_NODES) return;
    int beg = row_ptr[d], end = row_ptr[d + 1];
    float sp = 0.f;
    for (int c = beg + lane; c < end; c += 64) sp += p[csr_src[c]];
#pragma unroll
    for (int m = 32; m >= 1; m >>= 1) sp += __shfl_xor(sp, m, 64);
    if (lane == 0) evec[d] = __expf(sp + base[d]);
}

// ---------- graph boundaries from sorted batch ----------
__global__ __launch_bounds__(256) void k_bounds(const int* __restrict__ batch,
        int* __restrict__ gstart) {
    int n = blockIdx.x * 256 + threadIdx.x;
    if (n >= N_NODES) return;
    int bn = batch[n];
    int bp = (n == 0) ? -1 : batch[n - 1];
    for (int g = bp + 1; g <= bn; ++g) gstart[g] = n;
    if (n == N_NODES - 1)
        for (int g = bn + 1; g <= NG; ++g) gstart[g] = N_NODES;
}

// ---------- K4: per-graph pooled embedding (segmented reduce, no atomics) ----
__global__ __launch_bounds__(256) void k_pool(const float* __restrict__ x,
        const float* __restrict__ evec, const int* __restrict__ gstart,
        float* __restrict__ emb) {
    int g = blockIdx.x;
    int lane = threadIdx.x & 63;
    int wave = threadIdx.x >> 6;
    int beg = gstart[g], end = gstart[g + 1];
    float acc = 0.f, esum = 0.f;
    for (int n = beg + wave; n < end; n += 4) {
        float ev = evec[n];
        acc += ev * x[(size_t)n * HDIM + lane];
        esum += ev;
    }
    __shared__ float sacc[4][HDIM];
    __shared__ float ses[4];
    sacc[wave][lane] = acc;
    if (lane == 0) ses[wave] = esum;
    __syncthreads();
    if (wave == 0) {
        float a = sacc[0][lane] + sacc[1][lane] + sacc[2][lane] + sacc[3][lane];
        float es = ses[0] + ses[1] + ses[2] + ses[3];
        emb[(size_t)g * HDIM + lane] = (es > 0.f) ? (a / es) : 0.f;
    }
}

extern "C" void kernel_launch(void* const* d_in, const int* in_sizes, int n_in,
                              void* d_out, int out_size, void* d_ws, size_t ws_size,
                              hipStream_t stream) {
    const float* node  = (const float*)d_in[0];
    const int*   ei    = (const int*)d_in[1];
    const int*   batch = (const int*)d_in[2];
    const float* Wg    = (const float*)d_in[3];
    const float* att_s = (const float*)d_in[4];
    const float* att_d = (const float*)d_in[5];
    const float* bias  = (const float*)d_in[6];
    const float* wrel  = (const float*)d_in[7];
    const float* brel  = (const float*)d_in[8];
    const float* wroot = (const float*)d_in[9];

    float* out = (float*)d_out;
    float* emb = out + (size_t)N_NODES * HDIM;

    float* ws     = (float*)d_ws;
    float* xw     = ws;
    float* a_src  = ws + 6400000;
    float* a_dst  = ws + 6600000;
    float* p      = ws + 6800000;
    float* base   = ws + 6900000;
    float* evec   = ws + 7000000;
    int*   deg    = (int*)(ws + 7100000);
    int*   cur    = (int*)(ws + 7200000);
    int*   rowp   = (int*)(ws + 7300000);
    int*   bsum   = (int*)(ws + 7400008);
    int*   boff   = (int*)(ws + 7400400);
    int*   gstart = (int*)(ws + 7400792);
    int*   csrs   = (int*)(ws + 7402848);

    // zero deg + cur (contiguous 200,000 ints)
    hipMemsetAsync(deg, 0, 200000 * sizeof(int), stream);

    k_gemm<<<6250, 256, 0, stream>>>(node, Wg, att_s, att_d, xw, a_src, a_dst);
    k_bounds<<<(N_NODES + 255) / 256, 256, 0, stream>>>(batch, gstart);
    k_count<<<(NE + 255) / 256, 256, 0, stream>>>(ei, deg);
    k_blksum<<<SCAN_BLKS, 256, 0, stream>>>(deg, bsum);
    k_scan_bsum<<<1, 64, 0, stream>>>(bsum, boff);
    k_scan_final<<<SCAN_BLKS, 256, 0, stream>>>(deg, boff, rowp);
    k_scatter<<<(NE + 255) / 256, 256, 0, stream>>>(ei, rowp, cur, csrs);
    k_gat<<<(N_NODES + 3) / 4, 256, 0, stream>>>(rowp, csrs, xw, a_src, a_dst,
                                                 bias, wrel, wroot, brel,
                                                 out, p, base);
    k_score<<<(N_NODES + 3) / 4, 256, 0, stream>>>(rowp, csrs, p, base, evec);
    k_pool<<<NG, 256, 0, stream>>>(out, evec, gstart, emb);
}

// Round 3
// 440.449 us; speedup vs baseline: 1.9454x; 1.2733x over previous
//
#include <hip/hip_runtime.h>

#define N_NODES 100000
#define F_IN    128
#define HDIM    64
#define NE      1600000
#define NG      2048
#define NEG_SLOPE 0.2f
#define SCAN_BLKS 392   // 392*256 >= 100000

// ws layout (element offsets, 4B each)
//   xw      : 0         [N*64]
//   a_src   : 6,400,000 [N*2]
//   a_dst   : 6,600,000 [N*2]
//   p       : 6,800,000 [N]
//   base    : 6,900,000 [N]
//   evec    : 7,000,000 [N]
//   deg     : 7,100,000 [N]      (int, zeroed)
//   cur     : 7,200,000 [N]      (int, zeroed)
//   row_ptr : 7,300,000 [N+1]    (int)
//   bsum    : 7,400,008 [392]    (int)
//   boff    : 7,400,400 [392]    (int)
//   gstart  : 7,400,792 [NG+1]   (int)
//   csr_src : 7,402,848 [NE]     (int)

// ---------- K1: xw = node @ W_gat ; a_src/a_dst per (node, head) ----------
// 64 rows/block, 16 rows/wave (4 chunks of 4), W staged in LDS.
// launch_bounds(256,4) caps VGPR at 128 -> 4 waves/SIMD; unroll 4 keeps
// liveness bounded (round-2 version fully unrolled K=128 -> 256 VGPR, 8% occ).
__global__ __launch_bounds__(256, 4) void k_gemm(const float* __restrict__ node,
        const float* __restrict__ Wg, const float* __restrict__ att_s,
        const float* __restrict__ att_d, float* __restrict__ xw,
        float* __restrict__ a_src, float* __restrict__ a_dst) {
    __shared__ float WL[F_IN * HDIM];   // 32 KB
    int t = threadIdx.x;
    for (int i = t; i < F_IN * HDIM / 4; i += 256)
        ((float4*)WL)[i] = ((const float4*)Wg)[i];
    __syncthreads();

    int lane = t & 63;
    int wave = t >> 6;
    float asv = att_s[lane];
    float adv = att_d[lane];

    int wbase = blockIdx.x * 64 + wave * 16;   // 16 rows per wave
    for (int chunk = 0; chunk < 4; ++chunk) {
        int r0 = wbase + chunk * 4;            // N % 16 == 0 -> all-or-nothing
        if (r0 >= N_NODES) break;
        const float* n0 = node + (size_t)r0 * F_IN;

        float acc0 = 0.f, acc1 = 0.f, acc2 = 0.f, acc3 = 0.f;
#pragma unroll 4
        for (int k = 0; k < F_IN; k += 4) {
            float w0 = WL[(k + 0) * HDIM + lane];
            float w1 = WL[(k + 1) * HDIM + lane];
            float w2 = WL[(k + 2) * HDIM + lane];
            float w3 = WL[(k + 3) * HDIM + lane];
            float4 v;
            v = *(const float4*)(n0 + 0 * F_IN + k);
            acc0 += v.x * w0 + v.y * w1 + v.z * w2 + v.w * w3;
            v = *(const float4*)(n0 + 1 * F_IN + k);
            acc1 += v.x * w0 + v.y * w1 + v.z * w2 + v.w * w3;
            v = *(const float4*)(n0 + 2 * F_IN + k);
            acc2 += v.x * w0 + v.y * w1 + v.z * w2 + v.w * w3;
            v = *(const float4*)(n0 + 3 * F_IN + k);
            acc3 += v.x * w0 + v.y * w1 + v.z * w2 + v.w * w3;
        }

        float accs[4] = {acc0, acc1, acc2, acc3};
#pragma unroll
        for (int i = 0; i < 4; ++i) {
            int r = r0 + i;
            xw[(size_t)r * HDIM + lane] = accs[i];
            float sv = accs[i] * asv;
            float dv = accs[i] * adv;
#pragma unroll
            for (int m = 16; m >= 1; m >>= 1) {
                sv += __shfl_xor(sv, m, 32);
                dv += __shfl_xor(dv, m, 32);
            }
            if ((lane & 31) == 0) {
                a_src[r * 2 + (lane >> 5)] = sv;
                a_dst[r * 2 + (lane >> 5)] = dv;
            }
        }
    }
}

// ---------- CSR build ----------
__global__ __launch_bounds__(256) void k_count(const int* __restrict__ ei,
        int* __restrict__ deg) {
    int e = blockIdx.x * 256 + threadIdx.x;
    if (e >= NE) return;
    atomicAdd(&deg[ei[NE + e]], 1);
}

__global__ __launch_bounds__(256) void k_blksum(const int* __restrict__ deg,
        int* __restrict__ bsum) {
    int t = threadIdx.x, b = blockIdx.x;
    int i = b * 256 + t;
    int v = (i < N_NODES) ? deg[i] : 0;
#pragma unroll
    for (int m = 32; m >= 1; m >>= 1) v += __shfl_xor(v, m, 64);
    __shared__ int ws4[4];
    if ((t & 63) == 0) ws4[t >> 6] = v;
    __syncthreads();
    if (t == 0) bsum[b] = ws4[0] + ws4[1] + ws4[2] + ws4[3];
}

__global__ __launch_bounds__(64) void k_scan_bsum(const int* __restrict__ bsum,
        int* __restrict__ boff) {
    int lane = threadIdx.x;
    int carry = 0;
    for (int c = 0; c < SCAN_BLKS; c += 64) {
        int orig = (c + lane < SCAN_BLKS) ? bsum[c + lane] : 0;
        int incl = orig;
#pragma unroll
        for (int d = 1; d < 64; d <<= 1) {
            int u = __shfl_up(incl, d, 64);
            if (lane >= d) incl += u;
        }
        if (c + lane < SCAN_BLKS) boff[c + lane] = carry + incl - orig;
        carry += __shfl(incl, 63, 64);
    }
}

__global__ __launch_bounds__(256) void k_scan_final(const int* __restrict__ deg,
        const int* __restrict__ boff, int* __restrict__ row_ptr) {
    int t = threadIdx.x, b = blockIdx.x;
    int i = b * 256 + t;
    int v = (i < N_NODES) ? deg[i] : 0;
    int lane = t & 63, w = t >> 6;
    int incl = v;
#pragma unroll
    for (int d = 1; d < 64; d <<= 1) {
        int u = __shfl_up(incl, d, 64);
        if (lane >= d) incl += u;
    }
    __shared__ int wsum[4];
    if (lane == 63) wsum[w] = incl;
    __syncthreads();
    int wb = 0;
    for (int k = 0; k < w; ++k) wb += wsum[k];
    if (i < N_NODES) row_ptr[i] = boff[b] + wb + incl - v;
    if (b == 0 && t == 0) row_ptr[N_NODES] = NE;
}

__global__ __launch_bounds__(256) void k_scatter(const int* __restrict__ ei,
        const int* __restrict__ row_ptr, int* __restrict__ cur,
        int* __restrict__ csr_src) {
    int e = blockIdx.x * 256 + threadIdx.x;
    if (e >= NE) return;
    int d = ei[NE + e];
    int pos = atomicAdd(&cur[d], 1);
    csr_src[row_ptr[d] + pos] = ei[e];
}

// ---------- K2: GAT aggregation (gather over CSR) + fused norm/dots ----------
__global__ __launch_bounds__(256) void k_gat(const int* __restrict__ row_ptr,
        const int* __restrict__ csr_src, const float* __restrict__ xw,
        const float* __restrict__ a_src, const float* __restrict__ a_dst,
        const float* __restrict__ bias, const float* __restrict__ wrel,
        const float* __restrict__ wroot, const float* __restrict__ brel,
        float* __restrict__ x_out, float* __restrict__ p,
        float* __restrict__ base) {
    int lane = threadIdx.x & 63;
    int d = blockIdx.x * 4 + (threadIdx.x >> 6);
    if (d >= N_NODES) return;
    int h = lane >> 5;

    float ad0 = a_dst[d * 2];
    float ad1 = a_dst[d * 2 + 1];
    float as0d = a_src[d * 2];
    float as1d = a_src[d * 2 + 1];

    // self loop
    float lg = (h ? (as1d + ad1) : (as0d + ad0));
    lg = lg > 0.f ? lg : NEG_SLOPE * lg;
    float e = __expf(lg);
    float acc = e * xw[(size_t)d * HDIM + lane];
    float den = e;

    int beg = row_ptr[d], end = row_ptr[d + 1];
    for (int c = beg; c < end; c += 64) {
        int nv = end - c; if (nv > 64) nv = 64;
        int s_l = 0;
        float e0 = 0.f, e1 = 0.f;
        if (c + lane < end) {
            s_l = csr_src[c + lane];
            float as0 = a_src[s_l * 2];
            float as1 = a_src[s_l * 2 + 1];
            float l0 = as0 + ad0; l0 = l0 > 0.f ? l0 : NEG_SLOPE * l0;
            float l1 = as1 + ad1; l1 = l1 > 0.f ? l1 : NEG_SLOPE * l1;
            e0 = __expf(l0);
            e1 = __expf(l1);
        }
        for (int j = 0; j < nv; ++j) {
            int s = __shfl(s_l, j, 64);
            float ee0 = __shfl(e0, j, 64);
            float ee1 = __shfl(e1, j, 64);
            float ee = h ? ee1 : ee0;
            acc += ee * xw[(size_t)s * HDIM + lane];
            den += ee;
        }
    }

    float v = acc / den + bias[lane];
    x_out[(size_t)d * HDIM + lane] = v;

    float pv = v * wrel[lane];
    float rv = v * wroot[lane];
#pragma unroll
    for (int m = 32; m >= 1; m >>= 1) {
        pv += __shfl_xor(pv, m, 64);
        rv += __shfl_xor(rv, m, 64);
    }
    if (lane == 0) { p[d] = pv; base[d] = rv + brel[0]; }
}

// ---------- K3: score aggregation over CSR -> evec ----------
__global__ __launch_bounds__(256) void k_score(const int* __restrict__ row_ptr,
        const int* __restrict__ csr_src, const float* __restrict__ p,
        const float* __restrict__ base, float* __restrict__ evec) {
    int lane = threadIdx.x & 63;
    int d = blockIdx.x * 4 + (threadIdx.x >> 6);
    if (d >= N_NODES) return;
    int beg = row_ptr[d], end = row_ptr[d + 1];
    float sp = 0.f;
    for (int c = beg + lane; c < end; c += 64) sp += p[csr_src[c]];
#pragma unroll
    for (int m = 32; m >= 1; m >>= 1) sp += __shfl_xor(sp, m, 64);
    if (lane == 0) evec[d] = __expf(sp + base[d]);
}

// ---------- graph boundaries from sorted batch ----------
__global__ __launch_bounds__(256) void k_bounds(const int* __restrict__ batch,
        int* __restrict__ gstart) {
    int n = blockIdx.x * 256 + threadIdx.x;
    if (n >= N_NODES) return;
    int bn = batch[n];
    int bp = (n == 0) ? -1 : batch[n - 1];
    for (int g = bp + 1; g <= bn; ++g) gstart[g] = n;
    if (n == N_NODES - 1)
        for (int g = bn + 1; g <= NG; ++g) gstart[g] = N_NODES;
}

// ---------- K4: per-graph pooled embedding (segmented reduce, no atomics) ----
__global__ __launch_bounds__(256) void k_pool(const float* __restrict__ x,
        const float* __restrict__ evec, const int* __restrict__ gstart,
        float* __restrict__ emb) {
    int g = blockIdx.x;
    int lane = threadIdx.x & 63;
    int wave = threadIdx.x >> 6;
    int beg = gstart[g], end = gstart[g + 1];
    float acc = 0.f, esum = 0.f;
    for (int n = beg + wave; n < end; n += 4) {
        float ev = evec[n];
        acc += ev * x[(size_t)n * HDIM + lane];
        esum += ev;
    }
    __shared__ float sacc[4][HDIM];
    __shared__ float ses[4];
    sacc[wave][lane] = acc;
    if (lane == 0) ses[wave] = esum;
    __syncthreads();
    if (wave == 0) {
        float a = sacc[0][lane] + sacc[1][lane] + sacc[2][lane] + sacc[3][lane];
        float es = ses[0] + ses[1] + ses[2] + ses[3];
        emb[(size_t)g * HDIM + lane] = (es > 0.f) ? (a / es) : 0.f;
    }
}

extern "C" void kernel_launch(void* const* d_in, const int* in_sizes, int n_in,
                              void* d_out, int out_size, void* d_ws, size_t ws_size,
                              hipStream_t stream) {
    const float* node  = (const float*)d_in[0];
    const int*   ei    = (const int*)d_in[1];
    const int*   batch = (const int*)d_in[2];
    const float* Wg    = (const float*)d_in[3];
    const float* att_s = (const float*)d_in[4];
    const float* att_d = (const float*)d_in[5];
    const float* bias  = (const float*)d_in[6];
    const float* wrel  = (const float*)d_in[7];
    const float* brel  = (const float*)d_in[8];
    const float* wroot = (const float*)d_in[9];

    float* out = (float*)d_out;
    float* emb = out + (size_t)N_NODES * HDIM;

    float* ws     = (float*)d_ws;
    float* xw     = ws;
    float* a_src  = ws + 6400000;
    float* a_dst  = ws + 6600000;
    float* p      = ws + 6800000;
    float* base   = ws + 6900000;
    float* evec   = ws + 7000000;
    int*   deg    = (int*)(ws + 7100000);
    int*   cur    = (int*)(ws + 7200000);
    int*   rowp   = (int*)(ws + 7300000);
    int*   bsum   = (int*)(ws + 7400008);
    int*   boff   = (int*)(ws + 7400400);
    int*   gstart = (int*)(ws + 7400792);
    int*   csrs   = (int*)(ws + 7402848);

    // zero deg + cur (contiguous 200,000 ints)
    hipMemsetAsync(deg, 0, 200000 * sizeof(int), stream);

    k_gemm<<<(N_NODES + 63) / 64, 256, 0, stream>>>(node, Wg, att_s, att_d, xw, a_src, a_dst);
    k_bounds<<<(N_NODES + 255) / 256, 256, 0, stream>>>(batch, gstart);
    k_count<<<(NE + 255) / 256, 256, 0, stream>>>(ei, deg);
    k_blksum<<<SCAN_BLKS, 256, 0, stream>>>(deg, bsum);
    k_scan_bsum<<<1, 64, 0, stream>>>(bsum, boff);
    k_scan_final<<<SCAN_BLKS, 256, 0, stream>>>(deg, boff, rowp);
    k_scatter<<<(NE + 255) / 256, 256, 0, stream>>>(ei, rowp, cur, csrs);
    k_gat<<<(N_NODES + 3) / 4, 256, 0, stream>>>(rowp, csrs, xw, a_src, a_dst,
                                                 bias, wrel, wroot, brel,
                                                 out, p, base);
    k_score<<<(N_NODES + 3) / 4, 256, 0, stream>>>(rowp, csrs, p, base, evec);
    k_pool<<<NG, 256, 0, stream>>>(out, evec, gstart, emb);
}